// Round 7
// baseline (31089.069 us; speedup 1.0000x reference)
//
#include <hip/hip_runtime.h>
#include <math.h>

#define T_STEPS 512
#define BATCH   64
#define INDIM   512
#define MEMDIM  512
#define NWG     256
#define NT      1024

// 4 independent groups of 64 WGs; group g scans batch rows [16g,16g+16)
// (batch rows are independent LSTMs -> sync domain shrinks 4x).
// CU c in group owns mem dims [8c,8c+8) -> 32 gate rows, fp32 weights
// LDS-stationary (131KB dynamic LDS). Thread = (gate-row gr, batch b, half q):
// q=0 dots the x half of K (computed BEFORE the epoch wait, overlaps stragglers),
// q=1 dots the h half (serial part). Partials pair-reduced in LDS.
// Per-group barrier: 8 leaves x 8 WGs -> root -> 8 broadcast flags
// (max 8 requesters per cache line anywhere).

#define SMEM_FLOATS (32*1028 + 2*32*17 + 8*16 + 32)

extern "C" __global__ void __launch_bounds__(NT, 1)
lstm_scan(const float* __restrict__ inputs, const float* __restrict__ h0,
          const float* __restrict__ c0,
          const float* __restrict__ W_ioux, const float* __restrict__ b_ioux,
          const float* __restrict__ W_iouh, const float* __restrict__ b_iouh,
          const float* __restrict__ W_fx,   const float* __restrict__ b_fx,
          const float* __restrict__ W_fh,   const float* __restrict__ b_fh,
          float* __restrict__ out, int* __restrict__ bar)
{
    extern __shared__ float smem[];
    float* W_s    = smem;                    // [32][1028] gate rows x (x|h)
    float* part   = smem + 32*1028;          // [2][32][17]
    float* c_s    = part + 2*32*17;          // [8][16]
    float* bias_s = c_s + 8*16;              // [32]

    const int tid   = threadIdx.x;
    const int wg    = blockIdx.x;
    const int grp   = wg >> 6;               // 0..3
    const int cu    = wg & 63;               // 0..63
    const int bbase = grp * 16;
    const int dbase = cu * 8;

    const int gr = tid >> 5;                 // gate row 0..31 (gate=gr>>3, d=gr&7)
    const int b  = (tid >> 1) & 15;          // batch row in group
    const int q  = tid & 1;                  // 0 = x half, 1 = h half

    // ---- stage weights (once; reused 512 steps) ----
    for (int i = tid; i < 32 * 256; i += NT) {
        int row = i >> 8;                    // 0..31
        int c4  = i & 255;
        int gate = row >> 3, d = row & 7;
        int mg = dbase + d;
        const float* src;
        if (c4 < 128) {
            const float* Wx = (gate < 3) ? (W_ioux + (size_t)(gate * 512 + mg) * INDIM)
                                         : (W_fx   + (size_t)mg * INDIM);
            src = Wx + c4 * 4;
        } else {
            const float* Wh = (gate < 3) ? (W_iouh + (size_t)(gate * 512 + mg) * MEMDIM)
                                         : (W_fh   + (size_t)mg * MEMDIM);
            src = Wh + (c4 - 128) * 4;
        }
        float4 v = *(const float4*)src;
        *(float4*)&W_s[row * 1028 + c4 * 4] = v;
    }
    if (tid < 32) {
        int gate = tid >> 3, d = tid & 7, mg = dbase + d;
        bias_s[tid] = (gate < 3) ? (b_ioux[gate * 512 + mg] + b_iouh[gate * 512 + mg])
                                 : (b_fx[mg] + b_fh[mg]);
    }
    if (tid < 128) {
        int d = tid & 7, bb = tid >> 3;
        c_s[d * 16 + bb] = c0[(size_t)(bbase + bb) * MEMDIM + dbase + d];
    }
    __syncthreads();

    const float4* wp = (const float4*)&W_s[gr * 1028] + q * 128;

    int* leafcnt = bar + grp * 1024 + (cu >> 3) * 32;
    int* rootcnt = bar + grp * 1024 + 256;
    int* myflag  = bar + grp * 1024 + 288 + (cu >> 3) * 32;
    int* flags   = bar + grp * 1024 + 288;      // 8 flags, 128B apart

    for (int t = 0; t < T_STEPS; ++t) {
        float4 acc = make_float4(0.f, 0.f, 0.f, 0.f);

        if (q == 0) {   // x half: no serial dependence; overlaps the wait below
            const float4* xp = (const float4*)(inputs + ((size_t)t * BATCH + bbase + b) * INDIM);
#pragma unroll 8
            for (int k = 0; k < 128; ++k) {
                float4 w = wp[k];
                float4 v = xp[k];
                acc.x += v.x * w.x; acc.y += v.y * w.y;
                acc.z += v.z * w.z; acc.w += v.w * w.w;
            }
        }

        if (t > 0) {    // wait for group epoch t (h_{t-1} visible)
            if (tid == 0) {
                while (__hip_atomic_load(myflag, __ATOMIC_RELAXED,
                                         __HIP_MEMORY_SCOPE_AGENT) < t) {
                    __builtin_amdgcn_s_sleep(1);
                }
                (void)__hip_atomic_load(myflag, __ATOMIC_ACQUIRE,
                                        __HIP_MEMORY_SCOPE_AGENT);
            }
            __syncthreads();
        }

        if (q == 1) {   // h half: the serial part (K=512)
            const float* hprev = (t == 0) ? h0 : (out + (size_t)(t - 1) * BATCH * MEMDIM);
            const float4* hp = (const float4*)(hprev + (size_t)(bbase + b) * MEMDIM);
#pragma unroll 8
            for (int k = 0; k < 128; ++k) {
                float4 w = wp[k];
                float4 v = hp[k];
                acc.x += v.x * w.x; acc.y += v.y * w.y;
                acc.z += v.z * w.z; acc.w += v.w * w.w;
            }
        }
        part[(q * 32 + gr) * 17 + b] = acc.x + acc.y + acc.z + acc.w;
        __syncthreads();

        // ---- reduce halves, activations, c/h update ----
        if (tid < 128) {
            int d = tid & 7, bb = tid >> 3;
            float iv = part[(d      ) * 17 + bb] + part[(32 + d      ) * 17 + bb] + bias_s[d];
            float ov = part[(8  + d ) * 17 + bb] + part[(32 + 8  + d ) * 17 + bb] + bias_s[8  + d];
            float uv = part[(16 + d ) * 17 + bb] + part[(32 + 16 + d ) * 17 + bb] + bias_s[16 + d];
            float fv = part[(24 + d ) * 17 + bb] + part[(32 + 24 + d ) * 17 + bb] + bias_s[24 + d];
            float ig = 1.f / (1.f + expf(-iv));
            float og = 1.f / (1.f + expf(-ov));
            float ug = tanhf(uv);
            float fg = 1.f / (1.f + expf(-fv));
            float cn = ig * ug + fg * c_s[d * 16 + bb];
            c_s[d * 16 + bb] = cn;
            float hn = og * tanhf(cn);
            int bg = bbase + bb, mg = dbase + d;
            out[((size_t)t * BATCH + bg) * MEMDIM + mg] = hn;
            if (t == T_STEPS - 1) {
                out[(size_t)T_STEPS * BATCH * MEMDIM + (size_t)bg * MEMDIM + mg] = cn;  // c_final
                out[(size_t)T_STEPS * BATCH * MEMDIM + (size_t)BATCH * MEMDIM
                    + (size_t)bg * MEMDIM + mg] = hn;                                   // h_final
            }
        }
        __syncthreads();   // h stores drained (vmcnt) before the release below

        // ---- arrive: 8x8 tree + broadcast flags (group-local) ----
        if (tid == 0) {
            int n = __hip_atomic_fetch_add(leafcnt, 1, __ATOMIC_ACQ_REL,
                                           __HIP_MEMORY_SCOPE_AGENT);
            if (n == 8 * (t + 1) - 1) {                 // last WG of leaf
                int m = __hip_atomic_fetch_add(rootcnt, 1, __ATOMIC_ACQ_REL,
                                               __HIP_MEMORY_SCOPE_AGENT);
                if (m == 8 * (t + 1) - 1) {             // last leaf -> broadcast
                    for (int l = 0; l < 8; ++l) {
                        __hip_atomic_store(flags + l * 32, t + 1, __ATOMIC_RELEASE,
                                           __HIP_MEMORY_SCOPE_AGENT);
                    }
                }
            }
        }
    }
}

extern "C" void kernel_launch(void* const* d_in, const int* in_sizes, int n_in,
                              void* d_out, int out_size, void* d_ws, size_t ws_size,
                              hipStream_t stream) {
    (void)in_sizes; (void)n_in; (void)out_size; (void)ws_size;
    const float* inputs = (const float*)d_in[0];
    const float* h0     = (const float*)d_in[1];
    const float* c0     = (const float*)d_in[2];
    const float* W_ioux = (const float*)d_in[3];
    const float* b_ioux = (const float*)d_in[4];
    const float* W_iouh = (const float*)d_in[5];
    const float* b_iouh = (const float*)d_in[6];
    const float* W_fx   = (const float*)d_in[7];
    const float* b_fx   = (const float*)d_in[8];
    const float* W_fh   = (const float*)d_in[9];
    const float* b_fh   = (const float*)d_in[10];
    float* out = (float*)d_out;
    int*   bar = (int*)d_ws;

    const size_t smem_bytes = SMEM_FLOATS * sizeof(float);   // ~133.5 KB
    (void)hipFuncSetAttribute((const void*)lstm_scan,
                              hipFuncAttributeMaxDynamicSharedMemorySize,
                              (int)smem_bytes);

    // zero barrier state: 4 groups x 4KB (ws is poisoned 0xAA before every launch)
    (void)hipMemsetAsync(d_ws, 0, 16384, stream);

    void* args[] = { (void*)&inputs, (void*)&h0, (void*)&c0,
                     (void*)&W_ioux, (void*)&b_ioux, (void*)&W_iouh, (void*)&b_iouh,
                     (void*)&W_fx, (void*)&b_fx, (void*)&W_fh, (void*)&b_fh,
                     (void*)&out, (void*)&bar };

    hipError_t err = hipLaunchCooperativeKernel((const void*)lstm_scan,
                                                dim3(NWG), dim3(NT),
                                                args, smem_bytes, stream);
    if (err != hipSuccess) {
        // fallback: plain launch (grid == CU count, 1 WG/CU -> co-resident)
        hipLaunchKernelGGL(lstm_scan, dim3(NWG), dim3(NT), smem_bytes, stream,
                           inputs, h0, c0, W_ioux, b_ioux, W_iouh, b_iouh,
                           W_fx, b_fx, W_fh, b_fh, out, bar);
    }
}

// Round 8
// 12710.204 us; speedup vs baseline: 2.4460x; 2.4460x over previous
//
#include <hip/hip_runtime.h>
#include <math.h>

#define T_STEPS 512
#define BATCH   64
#define INDIM   512
#define MEMDIM  512
#define NWG     256
#define NT      1024

// Round-6 structure (best so far): WG wg owns mem dims {2wg,2wg+1} -> 8 gate
// rows; 1024 threads = 4 K-quarters x (j8,bsub,wv); weights LDS-stationary;
// c in LDS; x-dot hoisted above the epoch wait.
// NEW this round: h exchanged via RELAXED agent-scope atomics (sc1 coherent
// path, serviced at the memory-side point) -> no acquire/release cache
// maintenance anywhere; barrier is an all-relaxed 16x16 tree + 16 broadcast
// flag lines. Ordering: __syncthreads drains h stores (vmcnt) before the
// arrive RMW; readers' sc1 loads can't see stale caches by construction.

extern "C" __global__ void __launch_bounds__(NT, 4)
lstm_scan(const float* __restrict__ inputs, const float* __restrict__ h0,
          const float* __restrict__ c0,
          const float* __restrict__ W_ioux, const float* __restrict__ b_ioux,
          const float* __restrict__ W_iouh, const float* __restrict__ b_iouh,
          const float* __restrict__ W_fx,   const float* __restrict__ b_fx,
          const float* __restrict__ W_fh,   const float* __restrict__ b_fh,
          float* __restrict__ out, int* __restrict__ bar)
{
    __shared__ __align__(16) float W_s[8][1028];  // 8 gate rows x 1024 (x|h), padded
    __shared__ float part_s[4][8][68];            // K-quarter partials
    __shared__ float c_s[2][64];
    __shared__ float bias_s[8];

    const int tid  = threadIdx.x;
    const int wg   = blockIdx.x;
    const int q    = tid >> 8;          // K-quarter 0..3
    const int r    = tid & 255;
    const int j8   = r & 7;             // gate row within WG
    const int bsub = (r >> 3) & 7;
    const int wv   = r >> 6;            // 0..3
    const int b0   = 16 * wv + bsub;
    const int b1   = b0 + 8;

    // ---- stage weights into LDS (once; reused 512 steps) ----
    for (int i = tid; i < 8 * 256; i += NT) {   // 256 float4 per row
        int row = i >> 8;
        int c4  = i & 255;
        int mloc = row >> 2, gate = row & 3;
        int mg = 2 * wg + mloc;
        const float* src;
        if (c4 < 128) {  // x-side weight
            const float* Wx = (gate < 3) ? (W_ioux + (size_t)(gate * 512 + mg) * INDIM)
                                         : (W_fx   + (size_t)mg * INDIM);
            src = Wx + c4 * 4;
        } else {         // h-side weight
            const float* Wh = (gate < 3) ? (W_iouh + (size_t)(gate * 512 + mg) * MEMDIM)
                                         : (W_fh   + (size_t)mg * MEMDIM);
            src = Wh + (c4 - 128) * 4;
        }
        float4 v = *(const float4*)src;
        *(float4*)&W_s[row][c4 * 4] = v;
    }
    if (tid < 8) {
        int mloc = tid >> 2, gate = tid & 3, mg = 2 * wg + mloc;
        bias_s[tid] = (gate < 3) ? (b_ioux[gate * 512 + mg] + b_iouh[gate * 512 + mg])
                                 : (b_fx[mg] + b_fh[mg]);
    }
    if (tid < 128) {
        int mloc = tid >> 6, b = tid & 63;
        c_s[mloc][b] = c0[b * MEMDIM + 2 * wg + mloc];
    }
    __syncthreads();

    const float4* wrowx = (const float4*)&W_s[j8][0] + q * 32;        // x quarter
    const float4* wrowh = (const float4*)&W_s[j8][0] + 128 + q * 32;  // h quarter

    // barrier layout (ints): leaves bar[g*32] g=0..15; root bar[512];
    // broadcast flags bar[576 + g*32]
    int* myflag = bar + 576 + (wg >> 4) * 32;

    for (int t = 0; t < T_STEPS; ++t) {
        // ---- x-side dot for step t (independent of h; overlaps the wait) ----
        const float4* x0p = (const float4*)(inputs + ((size_t)t * BATCH + b0) * INDIM) + q * 32;
        const float4* x1p = (const float4*)(inputs + ((size_t)t * BATCH + b1) * INDIM) + q * 32;
        float4 a0 = make_float4(0.f, 0.f, 0.f, 0.f);
        float4 a1 = make_float4(0.f, 0.f, 0.f, 0.f);
#pragma unroll 8
        for (int k = 0; k < 32; ++k) {
            float4 w  = wrowx[k];
            float4 v0 = x0p[k];
            float4 v1 = x1p[k];
            a0.x += v0.x * w.x; a0.y += v0.y * w.y; a0.z += v0.z * w.z; a0.w += v0.w * w.w;
            a1.x += v1.x * w.x; a1.y += v1.y * w.y; a1.z += v1.z * w.z; a1.w += v1.w * w.w;
        }

        // ---- wait for epoch t (h_{t-1} at coherence point) ----
        if (t > 0) {
            if (tid == 0) {
                while (__hip_atomic_load(myflag, __ATOMIC_RELAXED,
                                         __HIP_MEMORY_SCOPE_AGENT) < t) {
                    __builtin_amdgcn_s_sleep(1);
                }
            }
            __syncthreads();
        }

        // ---- h-side dot: coherent (sc1) u64 loads, bypass stale caches ----
        const float* hprev = (t == 0) ? h0 : (out + (size_t)(t - 1) * BATCH * MEMDIM);
        const unsigned long long* h0p =
            (const unsigned long long*)(hprev + (size_t)b0 * MEMDIM) + q * 64;
        const unsigned long long* h1p =
            (const unsigned long long*)(hprev + (size_t)b1 * MEMDIM) + q * 64;
#pragma unroll 8
        for (int k = 0; k < 32; ++k) {
            float4 w = wrowh[k];
            unsigned long long u0a = __hip_atomic_load(h0p + 2*k,     __ATOMIC_RELAXED, __HIP_MEMORY_SCOPE_AGENT);
            unsigned long long u0b = __hip_atomic_load(h0p + 2*k + 1, __ATOMIC_RELAXED, __HIP_MEMORY_SCOPE_AGENT);
            unsigned long long u1a = __hip_atomic_load(h1p + 2*k,     __ATOMIC_RELAXED, __HIP_MEMORY_SCOPE_AGENT);
            unsigned long long u1b = __hip_atomic_load(h1p + 2*k + 1, __ATOMIC_RELAXED, __HIP_MEMORY_SCOPE_AGENT);
            float2 f0a = __builtin_bit_cast(float2, u0a);
            float2 f0b = __builtin_bit_cast(float2, u0b);
            float2 f1a = __builtin_bit_cast(float2, u1a);
            float2 f1b = __builtin_bit_cast(float2, u1b);
            a0.x += f0a.x * w.x; a0.y += f0a.y * w.y; a0.z += f0b.x * w.z; a0.w += f0b.y * w.w;
            a1.x += f1a.x * w.x; a1.y += f1a.y * w.y; a1.z += f1b.x * w.z; a1.w += f1b.y * w.w;
        }
        part_s[q][j8][b0] = a0.x + a0.y + a0.z + a0.w;
        part_s[q][j8][b1] = a1.x + a1.y + a1.z + a1.w;
        __syncthreads();

        // ---- epilogue: reduce quarters, activations, c/h update ----
        if (tid < 128) {
            int mloc = tid >> 6, b = tid & 63;
            int gr = mloc * 4;
            float iv = part_s[0][gr+0][b] + part_s[1][gr+0][b] + part_s[2][gr+0][b] + part_s[3][gr+0][b] + bias_s[gr+0];
            float ov = part_s[0][gr+1][b] + part_s[1][gr+1][b] + part_s[2][gr+1][b] + part_s[3][gr+1][b] + bias_s[gr+1];
            float uv = part_s[0][gr+2][b] + part_s[1][gr+2][b] + part_s[2][gr+2][b] + part_s[3][gr+2][b] + bias_s[gr+2];
            float fv = part_s[0][gr+3][b] + part_s[1][gr+3][b] + part_s[2][gr+3][b] + part_s[3][gr+3][b] + bias_s[gr+3];
            float ig = 1.f / (1.f + expf(-iv));
            float og = 1.f / (1.f + expf(-ov));
            float ug = tanhf(uv);
            float fg = 1.f / (1.f + expf(-fv));
            float cn = ig * ug + fg * c_s[mloc][b];
            c_s[mloc][b] = cn;
            float hn = og * tanhf(cn);
            int mg = 2 * wg + mloc;
            // h write-through to the coherence point (readers load sc1)
            __hip_atomic_store(&out[((size_t)t * BATCH + b) * MEMDIM + mg], hn,
                               __ATOMIC_RELAXED, __HIP_MEMORY_SCOPE_AGENT);
            if (t == T_STEPS - 1) {
                out[(size_t)T_STEPS * BATCH * MEMDIM + (size_t)b * MEMDIM + mg] = cn;  // c_final
                out[(size_t)T_STEPS * BATCH * MEMDIM + (size_t)BATCH * MEMDIM
                    + (size_t)b * MEMDIM + mg] = hn;                                   // h_final
            }
        }
        __syncthreads();   // drains h stores (vmcnt) before the arrive below

        // ---- arrive: all-relaxed 16x16 tree + 16 broadcast flag lines ----
        if (tid == 0) {
            int g = wg >> 4;
            int n = __hip_atomic_fetch_add(&bar[g * 32], 1, __ATOMIC_RELAXED,
                                           __HIP_MEMORY_SCOPE_AGENT);
            if (n == 16 * (t + 1) - 1) {                 // last WG of this leaf
                int m = __hip_atomic_fetch_add(&bar[512], 1, __ATOMIC_RELAXED,
                                               __HIP_MEMORY_SCOPE_AGENT);
                if (m == 16 * (t + 1) - 1) {             // last leaf -> broadcast
                    for (int l = 0; l < 16; ++l) {
                        __hip_atomic_store(&bar[576 + l * 32], t + 1,
                                           __ATOMIC_RELAXED, __HIP_MEMORY_SCOPE_AGENT);
                    }
                }
            }
        }
    }
}

extern "C" void kernel_launch(void* const* d_in, const int* in_sizes, int n_in,
                              void* d_out, int out_size, void* d_ws, size_t ws_size,
                              hipStream_t stream) {
    (void)in_sizes; (void)n_in; (void)out_size; (void)ws_size;
    const float* inputs = (const float*)d_in[0];
    const float* h0     = (const float*)d_in[1];
    const float* c0     = (const float*)d_in[2];
    const float* W_ioux = (const float*)d_in[3];
    const float* b_ioux = (const float*)d_in[4];
    const float* W_iouh = (const float*)d_in[5];
    const float* b_iouh = (const float*)d_in[6];
    const float* W_fx   = (const float*)d_in[7];
    const float* b_fx   = (const float*)d_in[8];
    const float* W_fh   = (const float*)d_in[9];
    const float* b_fh   = (const float*)d_in[10];
    float* out = (float*)d_out;
    int*   bar = (int*)d_ws;

    // zero barrier state (ws is poisoned 0xAA before every launch)
    (void)hipMemsetAsync(d_ws, 0, 8192, stream);

    void* args[] = { (void*)&inputs, (void*)&h0, (void*)&c0,
                     (void*)&W_ioux, (void*)&b_ioux, (void*)&W_iouh, (void*)&b_iouh,
                     (void*)&W_fx, (void*)&b_fx, (void*)&W_fh, (void*)&b_fh,
                     (void*)&out, (void*)&bar };

    hipError_t err = hipLaunchCooperativeKernel((const void*)lstm_scan,
                                                dim3(NWG), dim3(NT),
                                                args, 0, stream);
    if (err != hipSuccess) {
        // fallback: plain launch (grid == CU count, 1 WG/CU -> co-resident)
        hipLaunchKernelGGL(lstm_scan, dim3(NWG), dim3(NT), 0, stream,
                           inputs, h0, c0, W_ioux, b_ioux, W_iouh, b_iouh,
                           W_fx, b_fx, W_fh, b_fh, out, bar);
    }
}

// Round 9
// 6463.561 us; speedup vs baseline: 4.8099x; 1.9664x over previous
//
#include <hip/hip_runtime.h>
#include <math.h>

#define T_STEPS 512
#define BATCH   64
#define INDIM   512
#define MEMDIM  512
#define NWG     256
#define NT      1024

// WG wg owns mem dims {2wg,2wg+1} (8 gate rows). Weights LDS-stationary.
// h exchange: transposed single-writer ws buffer hist[2][512][64] (relaxed
// agent-scope atomics; no false sharing; coalesced lane=batch reads).
// out[t][b][m] stores are DEFERRED past the barrier arrive (drain next step).
// x-dot hoisted above the epoch wait. All-relaxed 16x16 tree barrier.
// LDS (dynamic, 77KB): W_s[8][1028] | xpart[4][8][68] | hpart[16][8][68]
//                      | c_s[2][64] | bias_s[8]

#define SMEM_FLOATS (8*1028 + 4*8*68 + 16*8*68 + 2*64 + 8)

extern "C" __global__ void __launch_bounds__(NT, 1)
lstm_scan(const float* __restrict__ inputs, const float* __restrict__ h0,
          const float* __restrict__ c0,
          const float* __restrict__ W_ioux, const float* __restrict__ b_ioux,
          const float* __restrict__ W_iouh, const float* __restrict__ b_iouh,
          const float* __restrict__ W_fx,   const float* __restrict__ b_fx,
          const float* __restrict__ W_fh,   const float* __restrict__ b_fh,
          float* __restrict__ out, int* __restrict__ bar)
{
    extern __shared__ float smem[];
    float* W_s    = smem;                       // [8][1028]
    float* xpart  = smem + 8*1028;              // [4][8][68]
    float* hpart  = xpart + 4*8*68;             // [16][8][68]
    float* c_s    = hpart + 16*8*68;            // [2][64]
    float* bias_s = c_s + 2*64;                 // [8]

    float* hist = (float*)(bar + 2048);         // [2][512][64] at ws+8KB

    const int tid  = threadIdx.x;
    const int wg   = blockIdx.x;
    const int lane = tid & 63;
    const int wv16 = tid >> 6;          // wave 0..15

    // x-dot mapping (R6): quarter q, gate row j8, batch rows b0,b1
    const int q    = tid >> 8;
    const int r    = tid & 255;
    const int j8   = r & 7;
    const int bsub = (r >> 3) & 7;
    const int wv   = r >> 6;
    const int b0   = 16 * wv + bsub;
    const int b1   = b0 + 8;

    // h-dot mapping: wave owns dims [32*wv16, 32*wv16+32); lane=batch pair
    const int s    = lane & 31;         // batch pair index
    const int dsub = lane >> 5;         // 0/1

    // ---- stage weights into LDS (once) ----
    for (int i = tid; i < 8 * 256; i += NT) {
        int row = i >> 8;
        int c4  = i & 255;
        int mloc = row >> 2, gate = row & 3;
        int mg = 2 * wg + mloc;
        const float* src;
        if (c4 < 128) {
            const float* Wx = (gate < 3) ? (W_ioux + (size_t)(gate * 512 + mg) * INDIM)
                                         : (W_fx   + (size_t)mg * INDIM);
            src = Wx + c4 * 4;
        } else {
            const float* Wh = (gate < 3) ? (W_iouh + (size_t)(gate * 512 + mg) * MEMDIM)
                                         : (W_fh   + (size_t)mg * MEMDIM);
            src = Wh + (c4 - 128) * 4;
        }
        float4 v = *(const float4*)src;
        *(float4*)&W_s[row * 1028 + c4 * 4] = v;
    }
    if (tid < 8) {
        int mloc = tid >> 2, gate = tid & 3, mg = 2 * wg + mloc;
        bias_s[tid] = (gate < 3) ? (b_ioux[gate * 512 + mg] + b_iouh[gate * 512 + mg])
                                 : (b_fx[mg] + b_fh[mg]);
    }
    if (tid < 128) {
        int mloc = tid >> 6, b = tid & 63;
        c_s[mloc * 64 + b] = c0[(size_t)b * MEMDIM + 2 * wg + mloc];
        // prologue: transpose h0 slice into hist[0] (single-writer rows)
        float hv = h0[(size_t)b * MEMDIM + 2 * wg + mloc];
        __hip_atomic_store(&hist[(2 * wg + mloc) * 64 + b], hv,
                           __ATOMIC_RELAXED, __HIP_MEMORY_SCOPE_AGENT);
    }
    __syncthreads();   // LDS ready; hist[0] stores drained (vmcnt)

    // barrier: leaves bar[g*32] g<16; root bar[512]; flags bar[576+g*32]
    int* myflag = bar + 576 + (wg >> 4) * 32;
    if (tid == 0) {   // arrive epoch 1 (hist[0] ready)
        int n = __hip_atomic_fetch_add(&bar[(wg >> 4) * 32], 1, __ATOMIC_RELAXED,
                                       __HIP_MEMORY_SCOPE_AGENT);
        if (n == 15) {
            int m = __hip_atomic_fetch_add(&bar[512], 1, __ATOMIC_RELAXED,
                                           __HIP_MEMORY_SCOPE_AGENT);
            if (m == 15) {
                for (int l = 0; l < 16; ++l)
                    __hip_atomic_store(&bar[576 + l * 32], 1, __ATOMIC_RELAXED,
                                       __HIP_MEMORY_SCOPE_AGENT);
            }
        }
    }

    const float4* wrowx = (const float4*)&W_s[j8 * 1028] + q * 32;

    for (int t = 0; t < T_STEPS; ++t) {
        // ---- x-side dot (independent of h; overlaps the wait) ----
        const float4* x0p = (const float4*)(inputs + ((size_t)t * BATCH + b0) * INDIM) + q * 32;
        const float4* x1p = (const float4*)(inputs + ((size_t)t * BATCH + b1) * INDIM) + q * 32;
        float4 a0 = make_float4(0.f, 0.f, 0.f, 0.f);
        float4 a1 = make_float4(0.f, 0.f, 0.f, 0.f);
#pragma unroll 8
        for (int k = 0; k < 32; ++k) {
            float4 w  = wrowx[k];
            float4 v0 = x0p[k];
            float4 v1 = x1p[k];
            a0.x += v0.x * w.x; a0.y += v0.y * w.y; a0.z += v0.z * w.z; a0.w += v0.w * w.w;
            a1.x += v1.x * w.x; a1.y += v1.y * w.y; a1.z += v1.z * w.z; a1.w += v1.w * w.w;
        }
        xpart[q * 544 + j8 * 68 + b0] = a0.x + a0.y + a0.z + a0.w;
        xpart[q * 544 + j8 * 68 + b1] = a1.x + a1.y + a1.z + a1.w;

        // ---- wait for epoch t+1 (hist[t&1] complete) ----
        if (tid == 0) {
            while (__hip_atomic_load(myflag, __ATOMIC_RELAXED,
                                     __HIP_MEMORY_SCOPE_AGENT) < t + 1) {
                __builtin_amdgcn_s_sleep(1);
            }
        }
        __syncthreads();

        // ---- h-side dot: wave-owned 32-dim slice, lane=batch, coalesced ----
        const unsigned long long* hrow =
            (const unsigned long long*)(hist + (size_t)(t & 1) * 32768);
        float2 hacc[8];
#pragma unroll
        for (int j = 0; j < 8; ++j) { hacc[j].x = 0.f; hacc[j].y = 0.f; }
#pragma unroll 4
        for (int it = 0; it < 16; ++it) {
            int d = wv16 * 32 + it * 2 + dsub;
            unsigned long long u = __hip_atomic_load(hrow + d * 32 + s,
                                                     __ATOMIC_RELAXED,
                                                     __HIP_MEMORY_SCOPE_AGENT);
            float2 hv = __builtin_bit_cast(float2, u);
#pragma unroll
            for (int j = 0; j < 8; ++j) {
                float wj = W_s[j * 1028 + 512 + d];
                hacc[j].x += wj * hv.x;
                hacc[j].y += wj * hv.y;
            }
        }
#pragma unroll
        for (int j = 0; j < 8; ++j) {
            hacc[j].x += __shfl_xor(hacc[j].x, 32);
            hacc[j].y += __shfl_xor(hacc[j].y, 32);
        }
        if (lane < 32) {
#pragma unroll
            for (int j = 0; j < 8; ++j)
                *(float2*)&hpart[wv16 * 544 + j * 68 + 2 * s] = hacc[j];
        }
        __syncthreads();

        // ---- epilogue: reduce partials, activations, c/h update ----
        float hn = 0.f, cn = 0.f;
        int mloc = tid >> 6, b = tid & 63;
        if (tid < 128) {
            float g[4];
#pragma unroll
            for (int gi = 0; gi < 4; ++gi) {
                int j = mloc * 4 + gi;
                float v = bias_s[j];
#pragma unroll
                for (int qq = 0; qq < 4; ++qq) v += xpart[qq * 544 + j * 68 + b];
#pragma unroll
                for (int w = 0; w < 16; ++w)  v += hpart[w * 544 + j * 68 + b];
                g[gi] = v;
            }
            float ig = 1.f / (1.f + expf(-g[0]));
            float og = 1.f / (1.f + expf(-g[1]));
            float ug = tanhf(g[2]);
            float fg = 1.f / (1.f + expf(-g[3]));
            cn = ig * ug + fg * c_s[mloc * 64 + b];
            c_s[mloc * 64 + b] = cn;
            hn = og * tanhf(cn);
            // single-writer transposed h write (coherence point)
            __hip_atomic_store(&hist[(size_t)((t + 1) & 1) * 32768
                                     + (2 * wg + mloc) * 64 + b], hn,
                               __ATOMIC_RELAXED, __HIP_MEMORY_SCOPE_AGENT);
        }
        __syncthreads();   // drains hist stores before the release below

        // ---- arrive epoch t+2 (all-relaxed tree) ----
        if (tid == 0) {
            int g16 = wg >> 4;
            int n = __hip_atomic_fetch_add(&bar[g16 * 32], 1, __ATOMIC_RELAXED,
                                           __HIP_MEMORY_SCOPE_AGENT);
            if (n == 16 * (t + 2) - 1) {
                int m = __hip_atomic_fetch_add(&bar[512], 1, __ATOMIC_RELAXED,
                                               __HIP_MEMORY_SCOPE_AGENT);
                if (m == 16 * (t + 2) - 1) {
                    for (int l = 0; l < 16; ++l)
                        __hip_atomic_store(&bar[576 + l * 32], t + 2,
                                           __ATOMIC_RELAXED, __HIP_MEMORY_SCOPE_AGENT);
                }
            }
        }

        // ---- DEFERRED out stores (off the critical path; drain next step) ----
        if (tid < 128) {
            int mg = 2 * wg + mloc;
            out[((size_t)t * BATCH + b) * MEMDIM + mg] = hn;
            if (t == T_STEPS - 1) {
                out[(size_t)T_STEPS * BATCH * MEMDIM + (size_t)b * MEMDIM + mg] = cn;
                out[(size_t)T_STEPS * BATCH * MEMDIM + (size_t)BATCH * MEMDIM
                    + (size_t)b * MEMDIM + mg] = hn;
            }
        }
    }
}

extern "C" void kernel_launch(void* const* d_in, const int* in_sizes, int n_in,
                              void* d_out, int out_size, void* d_ws, size_t ws_size,
                              hipStream_t stream) {
    (void)in_sizes; (void)n_in; (void)out_size; (void)ws_size;
    const float* inputs = (const float*)d_in[0];
    const float* h0     = (const float*)d_in[1];
    const float* c0     = (const float*)d_in[2];
    const float* W_ioux = (const float*)d_in[3];
    const float* b_ioux = (const float*)d_in[4];
    const float* W_iouh = (const float*)d_in[5];
    const float* b_iouh = (const float*)d_in[6];
    const float* W_fx   = (const float*)d_in[7];
    const float* b_fx   = (const float*)d_in[8];
    const float* W_fh   = (const float*)d_in[9];
    const float* b_fh   = (const float*)d_in[10];
    float* out = (float*)d_out;
    int*   bar = (int*)d_ws;

    const size_t smem_bytes = SMEM_FLOATS * sizeof(float);   // ~77 KB
    (void)hipFuncSetAttribute((const void*)lstm_scan,
                              hipFuncAttributeMaxDynamicSharedMemorySize,
                              (int)smem_bytes);

    // zero barrier state (first 8KB of ws); hist needs no init
    (void)hipMemsetAsync(d_ws, 0, 8192, stream);

    void* args[] = { (void*)&inputs, (void*)&h0, (void*)&c0,
                     (void*)&W_ioux, (void*)&b_ioux, (void*)&W_iouh, (void*)&b_iouh,
                     (void*)&W_fx, (void*)&b_fx, (void*)&W_fh, (void*)&b_fh,
                     (void*)&out, (void*)&bar };

    hipError_t err = hipLaunchCooperativeKernel((const void*)lstm_scan,
                                                dim3(NWG), dim3(NT),
                                                args, smem_bytes, stream);
    if (err != hipSuccess) {
        hipLaunchKernelGGL(lstm_scan, dim3(NWG), dim3(NT), smem_bytes, stream,
                           inputs, h0, c0, W_ioux, b_ioux, W_iouh, b_iouh,
                           W_fx, b_fx, W_fh, b_fh, out, bar);
    }
}